// Round 4
// baseline (126.890 us; speedup 1.0000x reference)
//
#include <hip/hip_runtime.h>
#include <hip/hip_bf16.h>
#include <hip/hip_fp16.h>

#define N_BCH 8
#define N_ATM 10000
#define N_ELM 100
#define N_ATOMS_TOT 80000

typedef int   i4 __attribute__((ext_vector_type(4)));
typedef float f4 __attribute__((ext_vector_type(4)));
typedef unsigned int u32;

// R8: split stream-from-gather. n<8 (3b), i<10000 (14b), j<10000 (14b)
// pack losslessly into one u32: p = n | i<<3 | j<<17.
//  - prepass: PURE streaming (read 61.4 MB n/i/j, write 20.5 MB packed to ws)
//    + elm->u8 pack + out zeroing. Diagnostic: if this kernel is off the
//    ~6.3 TB/s floor, the environment caps streaming and we're at roofline.
//  - edge: hot loop reads only 2 streams (8 B/edge, 41 MB; packed half is
//    L3-hot from prepass). Decode ~6 VALU. Same per-thread edge order and
//    arithmetic as R4/R7 -> absmax stays 0.

__launch_bounds__(1024)
__global__ void prepass_kernel(const int* __restrict__ elm,
                               const int* __restrict__ edge_n,
                               const int* __restrict__ edge_i,
                               const int* __restrict__ edge_j,
                               u32* __restrict__ elm_u8,
                               u32* __restrict__ packed,
                               float* __restrict__ out,
                               int nE) {
    const int tid    = blockIdx.x * blockDim.x + threadIdx.x;
    const int stride = gridDim.x * blockDim.x;
    const int nvec   = nE >> 2;

    const i4* en4 = (const i4*)edge_n;
    const i4* ei4 = (const i4*)edge_i;
    const i4* ej4 = (const i4*)edge_j;
    i4* p4 = (i4*)packed;

    for (int v = tid; v < nvec; v += stride) {
        i4 nn = en4[v];
        i4 ii = ei4[v];
        i4 jj = ej4[v];
        i4 pp;
#pragma unroll
        for (int u = 0; u < 4; ++u)
            pp[u] = nn[u] | (ii[u] << 3) | (jj[u] << 17);
        p4[v] = pp;
    }
    // scalar tail (nE % 4)
    for (int e = (nvec << 2) + tid; e < nE; e += stride)
        packed[e] = (u32)edge_n[e] | ((u32)edge_i[e] << 3)
                  | ((u32)edge_j[e] << 17);

    // elm int32 -> u8 table (first 20000 threads: 4 atoms each)
    if (tid < N_ATOMS_TOT / 4) {
        i4 v = *(const i4*)(elm + 4 * tid);
        elm_u8[tid] = (u32)(v[0] & 0xff)
                    | ((u32)(v[1] & 0xff) << 8)
                    | ((u32)(v[2] & 0xff) << 16)
                    | ((u32)(v[3] & 0xff) << 24);
    }
    if (tid < N_BCH) out[tid] = 0.0f;
}

// Gather kernel: all divergent accesses in LDS; 2-stream main loop.
//   s_elm32 : 80000 B u8 element types (whole batch)
//   s_kr    : 100x half2(k,r) -> one ds_read_b32 per endpoint
// LDS ~79.1 KiB -> 2 blocks/CU x 1024 thr = 32 waves/CU.
__launch_bounds__(1024, 8)
__global__ void edge_kernel(const u32* __restrict__ elm_u8,
                            const float* __restrict__ kparam,
                            const float* __restrict__ radius,
                            const u32* __restrict__ packed,
                            const float* __restrict__ sod,
                            float* __restrict__ out,
                            int nE) {
    __shared__ u32 s_elm32[N_ATOMS_TOT / 4];   // 80000 B
    __shared__ __half2 s_kr[128];              // 512 B (100 used)
    __shared__ float s_red[16][N_BCH];         // 512 B

    // ---- stage elm table (int4-vectorized: 5000 x 16B) + kr half2 table ----
    {
        const i4* src = (const i4*)elm_u8;
        i4* dst = (i4*)s_elm32;
        for (int t = threadIdx.x; t < N_ATOMS_TOT / 16; t += 1024)
            dst[t] = src[t];
        if (threadIdx.x < N_ELM)
            s_kr[threadIdx.x] =
                __floats2half2_rn(kparam[threadIdx.x], radius[threadIdx.x]);
    }
    __syncthreads();

    const unsigned char* s_elm = (const unsigned char*)s_elm32;

    float acc[N_BCH];
#pragma unroll
    for (int b = 0; b < N_BCH; ++b) acc[b] = 0.0f;

    const int tid    = blockIdx.x * blockDim.x + threadIdx.x;
    const int stride = gridDim.x * blockDim.x;
    const int nvec   = nE >> 2;

    const i4* p4 = (const i4*)packed;
    const f4* s4 = (const f4*)sod;

#define PROCESS(pp, ss)                                                 \
    do {                                                                \
        _Pragma("unroll")                                               \
        for (int u = 0; u < 4; ++u) {                                   \
            u32 p = (u32)(pp)[u];                                       \
            int n = (int)(p & 7u);                                      \
            int base = n * N_ATM;                                       \
            int e_i = s_elm[base + (int)((p >> 3) & 0x3fffu)];          \
            int e_j = s_elm[base + (int)(p >> 17)];                     \
            __half2 krsum = __hadd2(s_kr[e_i], s_kr[e_j]);              \
            float kk = __low2float(krsum);                              \
            float R  = __high2float(krsum);                             \
            float dis = sqrtf((ss)[u]);                                 \
            float d   = fminf(dis - R, 0.0f);                           \
            float val = kk * d * d;                                     \
            _Pragma("unroll")                                           \
            for (int b = 0; b < N_BCH; ++b)                             \
                acc[b] += (n == b) ? val : 0.0f;                        \
        }                                                               \
    } while (0)

    // ---- 2-deep software-pipelined grid-stride loop (2 streams) ----
    int v = tid;
    if (v < nvec) {
        i4 ppA = p4[v];  f4 ssA = s4[v];
        int w = v + stride;
        while (w < nvec) {
            i4 ppB = p4[w];  f4 ssB = s4[w];   // prefetch next
            PROCESS(ppA, ssA);
            ppA = ppB; ssA = ssB;
            w += stride;
        }
        PROCESS(ppA, ssA);
    }

    // scalar tail (nE % 4)
    const int tail_start = nvec << 2;
    const int tail_n = nE - tail_start;
    if (tid < tail_n) {
        int e = tail_start + tid;
        u32 p = packed[e];
        int n = (int)(p & 7u);
        int base = n * N_ATM;
        int e_i = s_elm[base + (int)((p >> 3) & 0x3fffu)];
        int e_j = s_elm[base + (int)(p >> 17)];
        __half2 krsum = __hadd2(s_kr[e_i], s_kr[e_j]);
        float kk = __low2float(krsum);
        float R  = __high2float(krsum);
        float dis = sqrtf(sod[e]);
        float d   = fminf(dis - R, 0.0f);
        float val = kk * d * d;
#pragma unroll
        for (int b = 0; b < N_BCH; ++b)
            acc[b] += (n == b) ? val : 0.0f;
    }

#undef PROCESS

    // ---- two-phase wave reduction ----
    const int lane = threadIdx.x & 63;
    const int wave = threadIdx.x >> 6;   // 16 waves
#pragma unroll
    for (int off = 8; off <= 32; off <<= 1) {
#pragma unroll
        for (int b = 0; b < N_BCH; ++b)
            acc[b] += __shfl_xor(acc[b], off, 64);
    }
    const int j = lane >> 3;
    float x = acc[0];
#pragma unroll
    for (int b = 1; b < N_BCH; ++b) x = (j == b) ? acc[b] : x;
#pragma unroll
    for (int off = 1; off <= 4; off <<= 1)
        x += __shfl_xor(x, off, 64);

    if ((lane & 7) == 0) s_red[wave][j] = x;
    __syncthreads();
    if (threadIdx.x < N_BCH) {
        float t = 0.0f;
#pragma unroll
        for (int w = 0; w < 16; ++w) t += s_red[w][threadIdx.x];
        atomicAdd(&out[threadIdx.x], t);
    }
}

extern "C" void kernel_launch(void* const* d_in, const int* in_sizes, int n_in,
                              void* d_out, int out_size, void* d_ws, size_t ws_size,
                              hipStream_t stream) {
    const int*   elm    = (const int*)d_in[0];
    const int*   edge_n = (const int*)d_in[1];
    const int*   edge_i = (const int*)d_in[2];
    const int*   edge_j = (const int*)d_in[3];
    const float* sod    = (const float*)d_in[4];
    const float* kparam = (const float*)d_in[5];
    const float* radius = (const float*)d_in[6];
    float* out = (float*)d_out;
    const int nE = in_sizes[1];

    // ws layout: [0, 80000) elm_u8 table; [128K, 128K + 4*nE) packed edges
    u32* elm_u8 = (u32*)d_ws;
    u32* packed = (u32*)((char*)d_ws + (128 << 10));

    // prepass also zeroes out[] -> 2 dispatches total
    hipLaunchKernelGGL(prepass_kernel, dim3(512), dim3(1024), 0, stream,
                       elm, edge_n, edge_i, edge_j, elm_u8, packed, out, nE);
    // 512 blocks x 1024 thr: 2 blocks/CU resident, 32 waves/CU
    hipLaunchKernelGGL(edge_kernel, dim3(512), dim3(1024), 0, stream,
                       elm_u8, kparam, radius, packed, sod, out, nE);
}

// Round 5
// 123.973 us; speedup vs baseline: 1.0235x; 1.0235x over previous
//
#include <hip/hip_runtime.h>
#include <hip/hip_bf16.h>
#include <hip/hip_fp16.h>

#define N_BCH 8
#define N_ATM 10000
#define N_ELM 100
#define N_ATOMS_TOT 80000

typedef int   i4 __attribute__((ext_vector_type(4)));
typedef float f4 __attribute__((ext_vector_type(4)));

// R9: R7 champion structure + NON-TEMPORAL stream loads.
// Theory: harness poison-fills (256 MiB = exactly L3) leave L3 fully dirty;
// our 82 MB of stream reads then evict ~82 MB of dirty victims -> ~164 MB
// mixed R/W -> ~30us instead of ~13us (observed ~2.8-3 TB/s effective, both
// R7 and R8 calibrate to this). __builtin_nontemporal_load avoids allocating
// the once-used streams in cache -> no dirty-victim writeback during edge.
// elm_u8 staging reads stay cacheable (512 blocks reuse the same 80 KB).
// Same per-thread FP order as R4/R7 -> absmax stays 0.

// Pre-pass: pack elm (int32, values <100) into u8 table in ws (80000 B).
// Also zeroes the 8-float output (replaces the memset dispatch).
__launch_bounds__(256)
__global__ void pack_elm_kernel(const int* __restrict__ elm,
                                unsigned int* __restrict__ elm_u8,
                                float* __restrict__ out) {
    int t = blockIdx.x * blockDim.x + threadIdx.x;
    if (t < N_ATOMS_TOT / 4) {
        i4 v = *(const i4*)(elm + 4 * t);
        elm_u8[t] = (unsigned int)(v[0] & 0xff)
                  | ((unsigned int)(v[1] & 0xff) << 8)
                  | ((unsigned int)(v[2] & 0xff) << 16)
                  | ((unsigned int)(v[3] & 0xff) << 24);
    }
    if (blockIdx.x == 0 && threadIdx.x < N_BCH)
        out[threadIdx.x] = 0.0f;
}

// R4 champion structure: all divergent accesses in LDS, grid-stride main loop.
//   s_elm32 : 80000 B u8 element types (whole batch)
//   s_kr    : 100x half2(k,r) -> one ds_read_b32 per endpoint
// LDS ~79.1 KiB -> 2 blocks/CU x 1024 thr = 32 waves/CU.
__launch_bounds__(1024, 8)
__global__ void edge_kernel(const unsigned int* __restrict__ elm_u8,
                            const float* __restrict__ kparam,
                            const float* __restrict__ radius,
                            const int* __restrict__ edge_n,
                            const int* __restrict__ edge_i,
                            const int* __restrict__ edge_j,
                            const float* __restrict__ sod,
                            float* __restrict__ out,
                            int nE) {
    __shared__ unsigned int s_elm32[N_ATOMS_TOT / 4];  // 80000 B
    __shared__ __half2 s_kr[128];                      // 512 B (100 used)
    __shared__ float s_red[16][N_BCH];                 // 512 B

    // ---- stage elm table (int4-vectorized: 5000 x 16B) + kr half2 table ----
    // These reads are REUSED across 512 blocks -> keep them cacheable.
    {
        const i4* src = (const i4*)elm_u8;
        i4* dst = (i4*)s_elm32;
        for (int t = threadIdx.x; t < N_ATOMS_TOT / 16; t += 1024)
            dst[t] = src[t];
        if (threadIdx.x < N_ELM)
            s_kr[threadIdx.x] =
                __floats2half2_rn(kparam[threadIdx.x], radius[threadIdx.x]);
    }
    __syncthreads();

    const unsigned char* s_elm = (const unsigned char*)s_elm32;

    float acc[N_BCH];
#pragma unroll
    for (int b = 0; b < N_BCH; ++b) acc[b] = 0.0f;

    const int tid    = blockIdx.x * blockDim.x + threadIdx.x;
    const int stride = gridDim.x * blockDim.x;
    const int nvec   = nE >> 2;

    const i4* en4 = (const i4*)edge_n;
    const i4* ei4 = (const i4*)edge_i;
    const i4* ej4 = (const i4*)edge_j;
    const f4* s4  = (const f4*)sod;

#define PROCESS(nn, ii, jj, ss)                                         \
    do {                                                                \
        _Pragma("unroll")                                               \
        for (int u = 0; u < 4; ++u) {                                   \
            int n = (nn)[u];                                            \
            int base = n * N_ATM;                                       \
            int e_i = s_elm[base + (ii)[u]];                            \
            int e_j = s_elm[base + (jj)[u]];                            \
            __half2 krsum = __hadd2(s_kr[e_i], s_kr[e_j]);              \
            float kk = __low2float(krsum);                              \
            float R  = __high2float(krsum);                             \
            float dis = sqrtf((ss)[u]);                                 \
            float d   = fminf(dis - R, 0.0f);                           \
            float val = kk * d * d;                                     \
            _Pragma("unroll")                                           \
            for (int b = 0; b < N_BCH; ++b)                             \
                acc[b] += (n == b) ? val : 0.0f;                        \
        }                                                               \
    } while (0)

    // ---- 2-deep software-pipelined grid-stride loop, NT stream loads ----
    int v = tid;
    if (v < nvec) {
        i4 nnA = __builtin_nontemporal_load(&en4[v]);
        i4 iiA = __builtin_nontemporal_load(&ei4[v]);
        i4 jjA = __builtin_nontemporal_load(&ej4[v]);
        f4 ssA = __builtin_nontemporal_load(&s4[v]);
        int w = v + stride;
        while (w < nvec) {
            i4 nnB = __builtin_nontemporal_load(&en4[w]);   // prefetch next
            i4 iiB = __builtin_nontemporal_load(&ei4[w]);
            i4 jjB = __builtin_nontemporal_load(&ej4[w]);
            f4 ssB = __builtin_nontemporal_load(&s4[w]);
            PROCESS(nnA, iiA, jjA, ssA);
            nnA = nnB; iiA = iiB; jjA = jjB; ssA = ssB;
            w += stride;
        }
        PROCESS(nnA, iiA, jjA, ssA);
    }

    // scalar tail (nE % 4)
    const int tail_start = nvec << 2;
    const int tail_n = nE - tail_start;
    if (tid < tail_n) {
        int e = tail_start + tid;
        int n = __builtin_nontemporal_load(&edge_n[e]);
        int ie = __builtin_nontemporal_load(&edge_i[e]);
        int je = __builtin_nontemporal_load(&edge_j[e]);
        float se = __builtin_nontemporal_load(&sod[e]);
        int e_i = s_elm[n * N_ATM + ie];
        int e_j = s_elm[n * N_ATM + je];
        __half2 krsum = __hadd2(s_kr[e_i], s_kr[e_j]);
        float kk = __low2float(krsum);
        float R  = __high2float(krsum);
        float dis = sqrtf(se);
        float d   = fminf(dis - R, 0.0f);
        float val = kk * d * d;
#pragma unroll
        for (int b = 0; b < N_BCH; ++b)
            acc[b] += (n == b) ? val : 0.0f;
    }

#undef PROCESS

    // ---- two-phase wave reduction ----
    const int lane = threadIdx.x & 63;
    const int wave = threadIdx.x >> 6;   // 16 waves
#pragma unroll
    for (int off = 8; off <= 32; off <<= 1) {
#pragma unroll
        for (int b = 0; b < N_BCH; ++b)
            acc[b] += __shfl_xor(acc[b], off, 64);
    }
    const int j = lane >> 3;
    float x = acc[0];
#pragma unroll
    for (int b = 1; b < N_BCH; ++b) x = (j == b) ? acc[b] : x;
#pragma unroll
    for (int off = 1; off <= 4; off <<= 1)
        x += __shfl_xor(x, off, 64);

    if ((lane & 7) == 0) s_red[wave][j] = x;
    __syncthreads();
    if (threadIdx.x < N_BCH) {
        float t = 0.0f;
#pragma unroll
        for (int w = 0; w < 16; ++w) t += s_red[w][threadIdx.x];
        atomicAdd(&out[threadIdx.x], t);
    }
}

extern "C" void kernel_launch(void* const* d_in, const int* in_sizes, int n_in,
                              void* d_out, int out_size, void* d_ws, size_t ws_size,
                              hipStream_t stream) {
    const int*   elm    = (const int*)d_in[0];
    const int*   edge_n = (const int*)d_in[1];
    const int*   edge_i = (const int*)d_in[2];
    const int*   edge_j = (const int*)d_in[3];
    const float* sod    = (const float*)d_in[4];
    const float* kparam = (const float*)d_in[5];
    const float* radius = (const float*)d_in[6];
    float* out = (float*)d_out;
    const int nE = in_sizes[1];

    unsigned int* elm_u8 = (unsigned int*)d_ws;  // 80000 B packed u8 table

    // pack kernel also zeroes out[] -> no memset dispatch (2 nodes total)
    hipLaunchKernelGGL(pack_elm_kernel, dim3((N_ATOMS_TOT / 4 + 255) / 256),
                       dim3(256), 0, stream, elm, elm_u8, out);
    // 512 blocks x 1024 thr: 2 blocks/CU resident, 32 waves/CU (R4 champion)
    hipLaunchKernelGGL(edge_kernel, dim3(512), dim3(1024), 0, stream,
                       elm_u8, kparam, radius, edge_n, edge_i, edge_j, sod,
                       out, nE);
}

// Round 6
// 118.694 us; speedup vs baseline: 1.0690x; 1.0445x over previous
//
#include <hip/hip_runtime.h>
#include <hip/hip_bf16.h>
#include <hip/hip_fp16.h>

#define N_BCH 8
#define N_ATM 10000
#define N_ELM 100
#define N_ATOMS_TOT 80000

typedef int   i4 __attribute__((ext_vector_type(4)));
typedef float f4 __attribute__((ext_vector_type(4)));

// R10: revert R9's non-temporal loads -> back to R7 champion (116.9 us).
// Session ledger:
//  - R5: poison fills (2x256 MiB, ~83 us) are UNCONDITIONAL; fusing pack
//    into edge costs +8 us (each block re-reads 320 KB elm int32). -> 2-kernel.
//  - R6/R7: latency/MLP theory refuted (clean 2-deep pipeline = memset win only).
//  - R8: stream-split refuted (+41 MB real traffic, -10 us).
//  - R9: NT loads refuted (L3 is memory-side; nt can't stop allocation, and
//    it hurt L2 merging -> -7 us).
//  - Confirmed by calibration: 256 MiB poison exactly fills L3 with dirty
//    lines; our 82 MB of stream reads evict ~82 MB dirty victims -> ~164 MB
//    HBM traffic -> edge floor ~26 us (observed ~30). Unavoidable from shader.
// Model floor: 83 (fills) + 26 (edge) + 1.5 (pack) + ~2 (gaps) ~= 112.5 us.
// R7 at 116.9 is within ~4%.

// Pre-pass: pack elm (int32, values <100) into u8 table in ws (80000 B).
// Also zeroes the 8-float output (replaces the memset dispatch).
__launch_bounds__(256)
__global__ void pack_elm_kernel(const int* __restrict__ elm,
                                unsigned int* __restrict__ elm_u8,
                                float* __restrict__ out) {
    int t = blockIdx.x * blockDim.x + threadIdx.x;
    if (t < N_ATOMS_TOT / 4) {
        i4 v = *(const i4*)(elm + 4 * t);
        elm_u8[t] = (unsigned int)(v[0] & 0xff)
                  | ((unsigned int)(v[1] & 0xff) << 8)
                  | ((unsigned int)(v[2] & 0xff) << 16)
                  | ((unsigned int)(v[3] & 0xff) << 24);
    }
    if (blockIdx.x == 0 && threadIdx.x < N_BCH)
        out[threadIdx.x] = 0.0f;
}

// R4/R7 champion structure: all divergent accesses in LDS, grid-stride loop.
//   s_elm32 : 80000 B u8 element types (whole batch)
//   s_kr    : 100x half2(k,r) -> one ds_read_b32 per endpoint
// LDS ~79.1 KiB -> 2 blocks/CU x 1024 thr = 32 waves/CU.
__launch_bounds__(1024, 8)
__global__ void edge_kernel(const unsigned int* __restrict__ elm_u8,
                            const float* __restrict__ kparam,
                            const float* __restrict__ radius,
                            const int* __restrict__ edge_n,
                            const int* __restrict__ edge_i,
                            const int* __restrict__ edge_j,
                            const float* __restrict__ sod,
                            float* __restrict__ out,
                            int nE) {
    __shared__ unsigned int s_elm32[N_ATOMS_TOT / 4];  // 80000 B
    __shared__ __half2 s_kr[128];                      // 512 B (100 used)
    __shared__ float s_red[16][N_BCH];                 // 512 B

    // ---- stage kr first (issues its global loads early), then elm table ----
    {
        if (threadIdx.x < N_ELM)
            s_kr[threadIdx.x] =
                __floats2half2_rn(kparam[threadIdx.x], radius[threadIdx.x]);
        const i4* src = (const i4*)elm_u8;
        i4* dst = (i4*)s_elm32;
        for (int t = threadIdx.x; t < N_ATOMS_TOT / 16; t += 1024)
            dst[t] = src[t];
    }
    __syncthreads();

    const unsigned char* s_elm = (const unsigned char*)s_elm32;

    float acc[N_BCH];
#pragma unroll
    for (int b = 0; b < N_BCH; ++b) acc[b] = 0.0f;

    const int tid    = blockIdx.x * blockDim.x + threadIdx.x;
    const int stride = gridDim.x * blockDim.x;
    const int nvec   = nE >> 2;

    const i4* en4 = (const i4*)edge_n;
    const i4* ei4 = (const i4*)edge_i;
    const i4* ej4 = (const i4*)edge_j;
    const f4* s4  = (const f4*)sod;

#define PROCESS(nn, ii, jj, ss)                                         \
    do {                                                                \
        _Pragma("unroll")                                               \
        for (int u = 0; u < 4; ++u) {                                   \
            int n = (nn)[u];                                            \
            int base = n * N_ATM;                                       \
            int e_i = s_elm[base + (ii)[u]];                            \
            int e_j = s_elm[base + (jj)[u]];                            \
            __half2 krsum = __hadd2(s_kr[e_i], s_kr[e_j]);              \
            float kk = __low2float(krsum);                              \
            float R  = __high2float(krsum);                             \
            float dis = sqrtf((ss)[u]);                                 \
            float d   = fminf(dis - R, 0.0f);                           \
            float val = kk * d * d;                                     \
            _Pragma("unroll")                                           \
            for (int b = 0; b < N_BCH; ++b)                             \
                acc[b] += (n == b) ? val : 0.0f;                        \
        }                                                               \
    } while (0)

    // ---- 2-deep software-pipelined grid-stride loop ----
    int v = tid;
    if (v < nvec) {
        i4 nnA = en4[v];  i4 iiA = ei4[v];
        i4 jjA = ej4[v];  f4 ssA = s4[v];
        int w = v + stride;
        while (w < nvec) {
            i4 nnB = en4[w];  i4 iiB = ei4[w];   // prefetch next
            i4 jjB = ej4[w];  f4 ssB = s4[w];
            PROCESS(nnA, iiA, jjA, ssA);
            nnA = nnB; iiA = iiB; jjA = jjB; ssA = ssB;
            w += stride;
        }
        PROCESS(nnA, iiA, jjA, ssA);
    }

    // scalar tail (nE % 4)
    const int tail_start = nvec << 2;
    const int tail_n = nE - tail_start;
    if (tid < tail_n) {
        int e = tail_start + tid;
        int n = edge_n[e];
        int e_i = s_elm[n * N_ATM + edge_i[e]];
        int e_j = s_elm[n * N_ATM + edge_j[e]];
        __half2 krsum = __hadd2(s_kr[e_i], s_kr[e_j]);
        float kk = __low2float(krsum);
        float R  = __high2float(krsum);
        float dis = sqrtf(sod[e]);
        float d   = fminf(dis - R, 0.0f);
        float val = kk * d * d;
#pragma unroll
        for (int b = 0; b < N_BCH; ++b)
            acc[b] += (n == b) ? val : 0.0f;
    }

#undef PROCESS

    // ---- two-phase wave reduction ----
    const int lane = threadIdx.x & 63;
    const int wave = threadIdx.x >> 6;   // 16 waves
#pragma unroll
    for (int off = 8; off <= 32; off <<= 1) {
#pragma unroll
        for (int b = 0; b < N_BCH; ++b)
            acc[b] += __shfl_xor(acc[b], off, 64);
    }
    const int j = lane >> 3;
    float x = acc[0];
#pragma unroll
    for (int b = 1; b < N_BCH; ++b) x = (j == b) ? acc[b] : x;
#pragma unroll
    for (int off = 1; off <= 4; off <<= 1)
        x += __shfl_xor(x, off, 64);

    if ((lane & 7) == 0) s_red[wave][j] = x;
    __syncthreads();
    if (threadIdx.x < N_BCH) {
        float t = 0.0f;
#pragma unroll
        for (int w = 0; w < 16; ++w) t += s_red[w][threadIdx.x];
        atomicAdd(&out[threadIdx.x], t);
    }
}

extern "C" void kernel_launch(void* const* d_in, const int* in_sizes, int n_in,
                              void* d_out, int out_size, void* d_ws, size_t ws_size,
                              hipStream_t stream) {
    const int*   elm    = (const int*)d_in[0];
    const int*   edge_n = (const int*)d_in[1];
    const int*   edge_i = (const int*)d_in[2];
    const int*   edge_j = (const int*)d_in[3];
    const float* sod    = (const float*)d_in[4];
    const float* kparam = (const float*)d_in[5];
    const float* radius = (const float*)d_in[6];
    float* out = (float*)d_out;
    const int nE = in_sizes[1];

    unsigned int* elm_u8 = (unsigned int*)d_ws;  // 80000 B packed u8 table

    // pack kernel also zeroes out[] -> no memset dispatch (2 nodes total)
    hipLaunchKernelGGL(pack_elm_kernel, dim3((N_ATOMS_TOT / 4 + 255) / 256),
                       dim3(256), 0, stream, elm, elm_u8, out);
    // 512 blocks x 1024 thr: 2 blocks/CU resident, 32 waves/CU (R4 champion)
    hipLaunchKernelGGL(edge_kernel, dim3(512), dim3(1024), 0, stream,
                       elm_u8, kparam, radius, edge_n, edge_i, edge_j, sod,
                       out, nE);
}